// Round 20
// baseline (36.546 us; speedup 1.0000x reference)
//
#include <hip/hip_runtime.h>
#include <math.h>

#define HH 512
#define WW 512

typedef float f2 __attribute__((ext_vector_type(2)));
typedef float f4 __attribute__((ext_vector_type(4)));

// Compiler-only memory fence: pins LDS write->read order across lanes.
// Same-wave LDS ops execute in order in HW; without this the compiler may
// hoist cross-lane gathers above scatters (R18's absmax=1.0 failure mode).
#define WFENCE() asm volatile("" ::: "memory")

// per-wave LDS slice (word offsets): Y 16x68, Cb 8x36, Cr 8x36
#define YS3  68
#define CS3  36
#define OY   0
#define OCB  1088     // %32 == 0
#define OCR  1376     // %32 == 0
#define WSZ  1664     // 6656 B/wave -> 26624 B per 4-wave block -> 6 blocks/CU

static __device__ __forceinline__ f4 vclamp01x255(f4 v) {
    f4 z = 0.f, one = 1.f;
    return __builtin_elementwise_max(__builtin_elementwise_min(v, one), z) * 255.f;
}

__device__ __constant__ float YTAB[64] = {
    16,11,10,16,24,40,51,61,
    12,12,14,19,26,58,60,55,
    14,13,16,24,40,57,69,56,
    14,17,22,29,51,87,80,62,
    18,22,37,56,68,109,103,77,
    24,35,55,64,81,104,113,92,
    49,64,78,87,103,121,120,101,
    72,92,95,98,112,100,103,99};
__device__ __constant__ float CTAB[64] = {
    17,18,24,47,99,99,99,99,
    18,21,26,66,99,99,99,99,
    24,26,56,99,99,99,99,99,
    47,66,99,99,99,99,99,99,
    99,99,99,99,99,99,99,99,
    99,99,99,99,99,99,99,99,
    99,99,99,99,99,99,99,99,
    99,99,99,99,99,99,99,99};
// rn(1/qt): compile-time IEEE constants (constexpr fp32 division)
__device__ __constant__ float YINV[64] = {
    1.f/16,1.f/11,1.f/10,1.f/16,1.f/24,1.f/40,1.f/51,1.f/61,
    1.f/12,1.f/12,1.f/14,1.f/19,1.f/26,1.f/58,1.f/60,1.f/55,
    1.f/14,1.f/13,1.f/16,1.f/24,1.f/40,1.f/57,1.f/69,1.f/56,
    1.f/14,1.f/17,1.f/22,1.f/29,1.f/51,1.f/87,1.f/80,1.f/62,
    1.f/18,1.f/22,1.f/37,1.f/56,1.f/68,1.f/109,1.f/103,1.f/77,
    1.f/24,1.f/35,1.f/55,1.f/64,1.f/81,1.f/104,1.f/113,1.f/92,
    1.f/49,1.f/64,1.f/78,1.f/87,1.f/103,1.f/121,1.f/120,1.f/101,
    1.f/72,1.f/92,1.f/95,1.f/98,1.f/112,1.f/100,1.f/103,1.f/99};
__device__ __constant__ float CINV[64] = {
    1.f/17,1.f/18,1.f/24,1.f/47,1.f/99,1.f/99,1.f/99,1.f/99,
    1.f/18,1.f/21,1.f/26,1.f/66,1.f/99,1.f/99,1.f/99,1.f/99,
    1.f/24,1.f/26,1.f/56,1.f/99,1.f/99,1.f/99,1.f/99,1.f/99,
    1.f/47,1.f/66,1.f/99,1.f/99,1.f/99,1.f/99,1.f/99,1.f/99,
    1.f/99,1.f/99,1.f/99,1.f/99,1.f/99,1.f/99,1.f/99,1.f/99,
    1.f/99,1.f/99,1.f/99,1.f/99,1.f/99,1.f/99,1.f/99,1.f/99,
    1.f/99,1.f/99,1.f/99,1.f/99,1.f/99,1.f/99,1.f/99,1.f/99,
    1.f/99,1.f/99,1.f/99,1.f/99,1.f/99,1.f/99,1.f/99,1.f/99};

// WAVE-AUTONOMOUS, DENSE, FENCED (R19) + two LDS/store cuts:
//  - basis broadcast via v_readlane (VALU pipe) instead of 64 LDS reads
//  - plain stores (L2/L3 absorb; in+out = 192MB < 256MB L3) instead of NT
// One wave = 64x16 region = 16 Y + 4 Cb + 4 Cr blocks = 3 DCT passes x 8
// lane-groups. In-place 8x8 transposes, every cross-lane LDS exchange
// WFENCE'd. Markstein correctly-rounded quantize divide. Zero barriers.
// Bit-critical pre-round chains verbatim from verified R8/R10-R19.
__global__ __launch_bounds__(256) void jpeg_fused(const float* __restrict__ in,
                                                  float* __restrict__ out)
{
#pragma clang fp contract(off)
    __shared__ float Wall[4][WSZ];

    const int tid  = threadIdx.x;
    const int wid  = tid >> 6;
    const int lane = tid & 63;
    float* W = Wall[wid];

    const int wv    = blockIdx.x * 4 + wid;   // wave id = 64x16 region id
    const int b     = wv >> 8;                // 256 regions per image
    const int strip = (wv >> 3) & 31;
    const int seg   = wv & 7;
    const int h0    = strip * 16;
    const int w0    = seg * 64;
    const size_t plane = (size_t)HH * WW;

    const int rp  = lane >> 3;
    const int pr  = rp * 2;
    const int c8  = lane & 7;
    const int c4  = c8 * 4;
    const size_t grow   = ((size_t)b * 3 * HH + (size_t)(h0 + pr)) * WW + c4;
    const size_t gbase0 = grow + w0;
    const size_t gbase1 = grow + w0 + 32;

    const int g = lane >> 3, j = lane & 7;
    f2 As2[32];

    auto loadT = [&](f4* L, size_t gb) {
        L[0] = *(const f4*)(in + gb);
        L[1] = *(const f4*)(in + gb + WW);
        L[2] = *(const f4*)(in + gb + plane);
        L[3] = *(const f4*)(in + gb + plane + WW);
        L[4] = *(const f4*)(in + gb + 2 * plane);
        L[5] = *(const f4*)(in + gb + 2 * plane + WW);
    };

    auto stageT = [&](const f4* L, int P) {
#pragma clang fp contract(off)
        f4 r0 = vclamp01x255(L[0]), r1 = vclamp01x255(L[1]);
        f4 g0 = vclamp01x255(L[2]), g1 = vclamp01x255(L[3]);
        f4 b0 = vclamp01x255(L[4]), b1 = vclamp01x255(L[5]);
        // noblas matmul: left-assoc, separate rn mul/add (no fma)
        f4 y0  = ((r0 * 0.299f)     + (g0 * 0.587f))     + (b0 * 0.114f);
        f4 y1  = ((r1 * 0.299f)     + (g1 * 0.587f))     + (b1 * 0.114f);
        f4 cb0 = ((r0 * -0.168736f) + (g0 * -0.331264f)) + (b0 * 0.5f);
        f4 cb1 = ((r1 * -0.168736f) + (g1 * -0.331264f)) + (b1 * 0.5f);
        f4 cr0 = ((r0 * 0.5f)       + (g0 * -0.418688f)) + (b0 * -0.081312f);
        f4 cr1 = ((r1 * 0.5f)       + (g1 * -0.418688f)) + (b1 * -0.081312f);
        cb0 = cb0 + 128.f; cb1 = cb1 + 128.f;   // +SHIFT1 separate rn add
        cr0 = cr0 + 128.f; cr1 = cr1 + 128.f;
        y0 = y0 - 128.f;  y1 = y1 - 128.f;      // channel does blocks-128
        *(f4*)&W[OY + pr * YS3 + 32 * P + c4]       = y0;
        *(f4*)&W[OY + (pr + 1) * YS3 + 32 * P + c4] = y1;
        // np multi-axis mean: paired (p00+p01)+(p10+p11), true-div by 4
        f2 mb, mr;
        {
            float s01 = cb0.x + cb0.y, s23 = cb1.x + cb1.y;
            mb[0] = (s01 + s23) / 4.0f;
            float t01 = cb0.z + cb0.w, t23 = cb1.z + cb1.w;
            mb[1] = (t01 + t23) / 4.0f;
        }
        {
            float s01 = cr0.x + cr0.y, s23 = cr1.x + cr1.y;
            mr[0] = (s01 + s23) / 4.0f;
            float t01 = cr0.z + cr0.w, t23 = cr1.z + cr1.w;
            mr[1] = (t01 + t23) / 4.0f;
        }
        *(f2*)&W[OCB + rp * CS3 + 16 * P + c8 * 2] = mb;
        *(f2*)&W[OCR + rp * CS3 + 16 * P + c8 * 2] = mr;
    };

    // one 8x8 block at LDS base Rb with row stride S; in-place transposes,
    // each scatter->gather fenced
    auto dctBlock = [&](int Rb, int S, bool isY, bool isChroma) {
#pragma clang fp contract(off)
        float X[8];
#pragma unroll
        for (int x = 0; x < 8; ++x) {
            float v = W[Rb + x * S + j];
            X[x] = isChroma ? (v - 128.f) : v;
        }
        WFENCE();                              // all X reads before overwrite
        // pass1 (contract x): T1[y=j][u], ascending-x fmaf chains, packed
        f2 Tv[4];
#pragma unroll
        for (int m = 0; m < 4; ++m) {
            f2 a = {0.f, 0.f};
#pragma unroll
            for (int x = 0; x < 8; ++x) {
                f2 xx = {X[x], X[x]};
                a = __builtin_elementwise_fma(xx, As2[x * 4 + m], a);
            }
            Tv[m] = a;
        }
#pragma unroll
        for (int m = 0; m < 4; ++m) {          // scatter T1^T in place
            W[Rb + (2 * m) * S + j]     = Tv[m][0];
            W[Rb + (2 * m + 1) * S + j] = Tv[m][1];
        }
        WFENCE();                              // scatter before gather
        float Tt[8];
        {
            float4 a = *(const float4*)&W[Rb + j * S];
            float4 c = *(const float4*)&W[Rb + j * S + 4];
            Tt[0] = a.x; Tt[1] = a.y; Tt[2] = a.z; Tt[3] = a.w;
            Tt[4] = c.x; Tt[5] = c.y; Tt[6] = c.z; Tt[7] = c.w;
        }
        WFENCE();                              // gather before next scatter
        // pass2 (contract y): raw[u=j][v], ascending-y packed chains
        float R[8];
#pragma unroll
        for (int m = 0; m < 4; ++m) {
            f2 a = {0.f, 0.f};
#pragma unroll
            for (int y = 0; y < 8; ++y) {
                f2 tt = {Tt[y], Tt[y]};
                a = __builtin_elementwise_fma(tt, As2[y * 4 + m], a);
            }
            R[2 * m] = a[0]; R[2 * m + 1] = a[1];
        }
        // quantize row u=j: Markstein correctly-rounded div by invariant qt
        const float* QT = isY ? YTAB : CTAB;
        const float* QI = isY ? YINV : CINV;
        float qt[8], qi[8];
        {
            float4 a = *(const float4*)&QT[j * 8];
            float4 c = *(const float4*)&QT[j * 8 + 4];
            qt[0] = a.x; qt[1] = a.y; qt[2] = a.z; qt[3] = a.w;
            qt[4] = c.x; qt[5] = c.y; qt[6] = c.z; qt[7] = c.w;
            float4 ai = *(const float4*)&QI[j * 8];
            float4 ci = *(const float4*)&QI[j * 8 + 4];
            qi[0] = ai.x; qi[1] = ai.y; qi[2] = ai.z; qi[3] = ai.w;
            qi[4] = ci.x; qi[5] = ci.y; qi[6] = ci.z; qi[7] = ci.w;
        }
        const float RC = 0.70710678118654752440f;
        float au = (j == 0) ? RC : 1.0f;
        float G[8];
#pragma unroll
        for (int v = 0; v < 8; ++v) {
            float av    = (v == 0) ? RC : 1.0f;
            float a2    = au * av;             // ALPHA2 fp32 product
            float scale = a2 * 0.25f;          // _SCALE
            float dct   = scale * R[v];
            // xq = rn(dct/qt): Markstein (y = rn(1/qt) const)
            float yv  = qi[v];
            float q0  = dct * yv;
            float rr  = fmaf(-qt[v], q0, dct);
            float xq  = fmaf(rr, yv, q0);
            float rd    = rintf(xq);           // half-to-even
            float d     = xq - rd;
            float cube  = (d * d) * d;
            float qq    = rd + cube;
            float deq   = qq * qt[v];
            G[v] = deq * a2;
        }
#pragma unroll
        for (int v = 0; v < 8; ++v) W[Rb + v * S + j] = G[v];   // scatter G
        WFENCE();
        float Gt[8];
        {
            float4 a = *(const float4*)&W[Rb + j * S];
            float4 c = *(const float4*)&W[Rb + j * S + 4];
            Gt[0] = a.x; Gt[1] = a.y; Gt[2] = a.z; Gt[3] = a.w;
            Gt[4] = c.x; Gt[5] = c.y; Gt[6] = c.z; Gt[7] = c.w;
        }
        WFENCE();
        // IDCT pass1 (contract u): T2[x][v=j]
        f2 T2v[4];
#pragma unroll
        for (int m = 0; m < 4; ++m) {
            f2 a = {0.f, 0.f};
#pragma unroll
            for (int u = 0; u < 8; ++u) {
                f2 gg = {Gt[u], Gt[u]};
                a = __builtin_elementwise_fma(gg, As2[u * 4 + m], a);
            }
            T2v[m] = a;
        }
#pragma unroll
        for (int m = 0; m < 4; ++m) {          // scatter T2
            W[Rb + (2 * m) * S + j]     = T2v[m][0];
            W[Rb + (2 * m + 1) * S + j] = T2v[m][1];
        }
        WFENCE();
        float T2t[8];
        {
            float4 a = *(const float4*)&W[Rb + j * S];
            float4 c = *(const float4*)&W[Rb + j * S + 4];
            T2t[0] = a.x; T2t[1] = a.y; T2t[2] = a.z; T2t[3] = a.w;
            T2t[4] = c.x; T2t[5] = c.y; T2t[6] = c.z; T2t[7] = c.w;
        }
        WFENCE();
        // IDCT pass2 (contract v): out[x=j][y] = 0.25*sum + 128
        float O[8];
#pragma unroll
        for (int m = 0; m < 4; ++m) {
            f2 a = {0.f, 0.f};
#pragma unroll
            for (int v = 0; v < 8; ++v) {
                f2 tt = {T2t[v], T2t[v]};
                a = __builtin_elementwise_fma(tt, As2[v * 4 + m], a);
            }
            a = (a * 0.25f) + 128.f;
            O[2 * m] = a[0]; O[2 * m + 1] = a[1];
        }
        *(f4*)&W[Rb + j * S]     = (f4){O[0], O[1], O[2], O[3]};
        *(f4*)&W[Rb + j * S + 4] = (f4){O[4], O[5], O[6], O[7]};
    };

    auto outputT = [&](size_t gb, int P) {
#pragma clang fp contract(off)
        const float INV255 = 1.0f / 255.0f;
        f4 ya = *(const f4*)&W[OY + pr * YS3 + 32 * P + c4];
        f4 yb = *(const f4*)&W[OY + (pr + 1) * YS3 + 32 * P + c4];
        f2 cbp = *(const f2*)&W[OCB + rp * CS3 + 16 * P + c8 * 2];
        f2 crp = *(const f2*)&W[OCR + rp * CS3 + 16 * P + c8 * 2];
        float cb0 = cbp[0] - 128.f, cb1 = cbp[1] - 128.f;   // +SHIFT2 sep add
        float cr0 = crp[0] - 128.f, cr1 = crp[1] - 128.f;
        f4 cbm = {cb0, cb0, cb1, cb1};
        f4 crm = {cr0, cr0, cr1, cr1};
        f4 z = 0.f, m255 = 255.f;
#pragma unroll
        for (int row = 0; row < 2; ++row) {
            f4 yy = row ? yb : ya;
            f4 rv = yy + (crm * 1.402f);
            f4 gv = (yy + (cbm * -0.344136f)) + (crm * -0.714136f);
            f4 bv = yy + (cbm * 1.772f);
            rv = __builtin_elementwise_max(__builtin_elementwise_min(rv, m255), z) * INV255;
            gv = __builtin_elementwise_max(__builtin_elementwise_min(gv, m255), z) * INV255;
            bv = __builtin_elementwise_max(__builtin_elementwise_min(bv, m255), z) * INV255;
            size_t base = gb + (size_t)row * WW;
            *(f4*)(out + base)             = rv;   // plain stores: L2/L3 absorb
            *(f4*)(out + base + plane)     = gv;
            *(f4*)(out + base + 2 * plane) = bv;
        }
    };

    // ---- schedule --------------------------------------------------------
    f4 L1[6], L2[6];
    loadT(L1, gbase0);
    loadT(L2, gbase1);                 // all 12 loads in flight

    // basis (np-exact: int mult, fp64 pi-mult/div, fp64 cos, fp32 cast);
    // each lane computes its own element, broadcast via v_readlane (no LDS)
    {
        int x = lane >> 3, u = lane & 7;
        double arg = (double)((2 * x + 1) * u) * 3.14159265358979323846 / 16.0;
        int bvi = __float_as_int((float)cos(arg));
#pragma unroll
        for (int k = 0; k < 32; ++k) {
            As2[k][0] = __int_as_float(__builtin_amdgcn_readlane(bvi, 2 * k));
            As2[k][1] = __int_as_float(__builtin_amdgcn_readlane(bvi, 2 * k + 1));
        }
    }

    stageT(L1, 0);
    stageT(L2, 1);
    WFENCE();                          // stage visible before DCT reads

    // dense DCT: pass0/1 = Y block rows, pass2 = chroma (4 Cb + 4 Cr)
    dctBlock(OY + 0 * 544 + 8 * g, YS3, true, false);
    WFENCE();
    dctBlock(OY + 1 * 544 + 8 * g, YS3, true, false);
    WFENCE();
    {
        int Rb = (g < 4) ? (OCB + 8 * g) : (OCR + 8 * (g - 4));
        dctBlock(Rb, CS3, false, true);
    }
    WFENCE();                          // all results visible before output

    outputT(gbase0, 0);
    outputT(gbase1, 1);
}

extern "C" void kernel_launch(void* const* d_in, const int* in_sizes, int n_in,
                              void* d_out, int out_size, void* d_ws, size_t ws_size,
                              hipStream_t stream)
{
    const float* x = (const float*)d_in[0];
    float* o = (float*)d_out;
    int batch  = in_sizes[0] / (3 * HH * WW);   // 32
    int blocks = batch * 256 / 4;               // 2048
    jpeg_fused<<<blocks, 256, 0, stream>>>(x, o);
}

// Round 21
// 36.263 us; speedup vs baseline: 1.0078x; 1.0078x over previous
//
#include <hip/hip_runtime.h>
#include <math.h>

#define HH 512
#define WW 512

typedef float f2 __attribute__((ext_vector_type(2)));
typedef float f4 __attribute__((ext_vector_type(4)));

// Compiler-only memory fence: pins LDS write->read order across lanes.
// Same-wave LDS ops execute in order in HW; without this the compiler may
// hoist cross-lane gathers above scatters (R18's absmax=1.0 failure mode).
#define WFENCE() asm volatile("" ::: "memory")

// per-wave LDS slice (word offsets): Y 16x68, Cb 8x36, Cr 8x36
#define YS3  68
#define CS3  36
#define OY   0
#define OCB  1088     // %32 == 0
#define OCR  1376     // %32 == 0
#define WSZ  1664     // 6656 B/wave -> 26624 B per 4-wave block -> 6 blocks/CU

static __device__ __forceinline__ f4 vclamp01x255(f4 v) {
    f4 z = 0.f, one = 1.f;
    return __builtin_elementwise_max(__builtin_elementwise_min(v, one), z) * 255.f;
}

__device__ __constant__ float YTAB[64] = {
    16,11,10,16,24,40,51,61,
    12,12,14,19,26,58,60,55,
    14,13,16,24,40,57,69,56,
    14,17,22,29,51,87,80,62,
    18,22,37,56,68,109,103,77,
    24,35,55,64,81,104,113,92,
    49,64,78,87,103,121,120,101,
    72,92,95,98,112,100,103,99};
__device__ __constant__ float CTAB[64] = {
    17,18,24,47,99,99,99,99,
    18,21,26,66,99,99,99,99,
    24,26,56,99,99,99,99,99,
    47,66,99,99,99,99,99,99,
    99,99,99,99,99,99,99,99,
    99,99,99,99,99,99,99,99,
    99,99,99,99,99,99,99,99,
    99,99,99,99,99,99,99,99};
// rn(1/qt): compile-time IEEE constants (constexpr fp32 division)
__device__ __constant__ float YINV[64] = {
    1.f/16,1.f/11,1.f/10,1.f/16,1.f/24,1.f/40,1.f/51,1.f/61,
    1.f/12,1.f/12,1.f/14,1.f/19,1.f/26,1.f/58,1.f/60,1.f/55,
    1.f/14,1.f/13,1.f/16,1.f/24,1.f/40,1.f/57,1.f/69,1.f/56,
    1.f/14,1.f/17,1.f/22,1.f/29,1.f/51,1.f/87,1.f/80,1.f/62,
    1.f/18,1.f/22,1.f/37,1.f/56,1.f/68,1.f/109,1.f/103,1.f/77,
    1.f/24,1.f/35,1.f/55,1.f/64,1.f/81,1.f/104,1.f/113,1.f/92,
    1.f/49,1.f/64,1.f/78,1.f/87,1.f/103,1.f/121,1.f/120,1.f/101,
    1.f/72,1.f/92,1.f/95,1.f/98,1.f/112,1.f/100,1.f/103,1.f/99};
__device__ __constant__ float CINV[64] = {
    1.f/17,1.f/18,1.f/24,1.f/47,1.f/99,1.f/99,1.f/99,1.f/99,
    1.f/18,1.f/21,1.f/26,1.f/66,1.f/99,1.f/99,1.f/99,1.f/99,
    1.f/24,1.f/26,1.f/56,1.f/99,1.f/99,1.f/99,1.f/99,1.f/99,
    1.f/47,1.f/66,1.f/99,1.f/99,1.f/99,1.f/99,1.f/99,1.f/99,
    1.f/99,1.f/99,1.f/99,1.f/99,1.f/99,1.f/99,1.f/99,1.f/99,
    1.f/99,1.f/99,1.f/99,1.f/99,1.f/99,1.f/99,1.f/99,1.f/99,
    1.f/99,1.f/99,1.f/99,1.f/99,1.f/99,1.f/99,1.f/99,1.f/99,
    1.f/99,1.f/99,1.f/99,1.f/99,1.f/99,1.f/99,1.f/99,1.f/99};

// R19/R20 structure + LOCKSTEP Y-PAIR DCT: the two independent Y dctBlocks
// run phase-interleaved (both blocks' scatters -> ONE fence -> both gathers),
// halving the dependent LDS round-trip count on the Y path. Chroma block
// unchanged. One wave = 64x16 region, zero barriers, wave-private LDS,
// Markstein correctly-rounded quantize divide, readlane basis broadcast.
// Bit-critical pre-round chains verbatim from verified R8/R10-R20.
__global__ __launch_bounds__(256) void jpeg_fused(const float* __restrict__ in,
                                                  float* __restrict__ out)
{
#pragma clang fp contract(off)
    __shared__ float Wall[4][WSZ];

    const int tid  = threadIdx.x;
    const int wid  = tid >> 6;
    const int lane = tid & 63;
    float* W = Wall[wid];

    const int wv    = blockIdx.x * 4 + wid;   // wave id = 64x16 region id
    const int b     = wv >> 8;                // 256 regions per image
    const int strip = (wv >> 3) & 31;
    const int seg   = wv & 7;
    const int h0    = strip * 16;
    const int w0    = seg * 64;
    const size_t plane = (size_t)HH * WW;

    const int rp  = lane >> 3;
    const int pr  = rp * 2;
    const int c8  = lane & 7;
    const int c4  = c8 * 4;
    const size_t grow   = ((size_t)b * 3 * HH + (size_t)(h0 + pr)) * WW + c4;
    const size_t gbase0 = grow + w0;
    const size_t gbase1 = grow + w0 + 32;

    const int g = lane >> 3, j = lane & 7;
    f2 As2[32];

    auto loadT = [&](f4* L, size_t gb) {
        L[0] = *(const f4*)(in + gb);
        L[1] = *(const f4*)(in + gb + WW);
        L[2] = *(const f4*)(in + gb + plane);
        L[3] = *(const f4*)(in + gb + plane + WW);
        L[4] = *(const f4*)(in + gb + 2 * plane);
        L[5] = *(const f4*)(in + gb + 2 * plane + WW);
    };

    auto stageT = [&](const f4* L, int P) {
#pragma clang fp contract(off)
        f4 r0 = vclamp01x255(L[0]), r1 = vclamp01x255(L[1]);
        f4 g0 = vclamp01x255(L[2]), g1 = vclamp01x255(L[3]);
        f4 b0 = vclamp01x255(L[4]), b1 = vclamp01x255(L[5]);
        // noblas matmul: left-assoc, separate rn mul/add (no fma)
        f4 y0  = ((r0 * 0.299f)     + (g0 * 0.587f))     + (b0 * 0.114f);
        f4 y1  = ((r1 * 0.299f)     + (g1 * 0.587f))     + (b1 * 0.114f);
        f4 cb0 = ((r0 * -0.168736f) + (g0 * -0.331264f)) + (b0 * 0.5f);
        f4 cb1 = ((r1 * -0.168736f) + (g1 * -0.331264f)) + (b1 * 0.5f);
        f4 cr0 = ((r0 * 0.5f)       + (g0 * -0.418688f)) + (b0 * -0.081312f);
        f4 cr1 = ((r1 * 0.5f)       + (g1 * -0.418688f)) + (b1 * -0.081312f);
        cb0 = cb0 + 128.f; cb1 = cb1 + 128.f;   // +SHIFT1 separate rn add
        cr0 = cr0 + 128.f; cr1 = cr1 + 128.f;
        y0 = y0 - 128.f;  y1 = y1 - 128.f;      // channel does blocks-128
        *(f4*)&W[OY + pr * YS3 + 32 * P + c4]       = y0;
        *(f4*)&W[OY + (pr + 1) * YS3 + 32 * P + c4] = y1;
        // np multi-axis mean: paired (p00+p01)+(p10+p11), true-div by 4
        f2 mb, mr;
        {
            float s01 = cb0.x + cb0.y, s23 = cb1.x + cb1.y;
            mb[0] = (s01 + s23) / 4.0f;
            float t01 = cb0.z + cb0.w, t23 = cb1.z + cb1.w;
            mb[1] = (t01 + t23) / 4.0f;
        }
        {
            float s01 = cr0.x + cr0.y, s23 = cr1.x + cr1.y;
            mr[0] = (s01 + s23) / 4.0f;
            float t01 = cr0.z + cr0.w, t23 = cr1.z + cr1.w;
            mr[1] = (t01 + t23) / 4.0f;
        }
        *(f2*)&W[OCB + rp * CS3 + 16 * P + c8 * 2] = mb;
        *(f2*)&W[OCR + rp * CS3 + 16 * P + c8 * 2] = mr;
    };

    // --- shared helpers for the matrix passes --------------------------
    auto pass8 = [&](const float* Xv, float* Rv) {     // Rv[u] = chain(Xv)
#pragma clang fp contract(off)
#pragma unroll
        for (int m = 0; m < 4; ++m) {
            f2 a = {0.f, 0.f};
#pragma unroll
            for (int k = 0; k < 8; ++k) {
                f2 xx = {Xv[k], Xv[k]};
                a = __builtin_elementwise_fma(xx, As2[k * 4 + m], a);
            }
            Rv[2 * m] = a[0]; Rv[2 * m + 1] = a[1];
        }
    };
    auto scat = [&](int Rb, int S, const float* V) {   // scatter V^T in place
#pragma unroll
        for (int v = 0; v < 8; ++v) W[Rb + v * S + j] = V[v];
    };
    auto gath = [&](int Rb, int S, float* V) {         // gather row j
        float4 a = *(const float4*)&W[Rb + j * S];
        float4 c = *(const float4*)&W[Rb + j * S + 4];
        V[0] = a.x; V[1] = a.y; V[2] = a.z; V[3] = a.w;
        V[4] = c.x; V[5] = c.y; V[6] = c.z; V[7] = c.w;
    };
    auto quant = [&](const float* R, float* G, bool isY) {
#pragma clang fp contract(off)
        const float* QT = isY ? YTAB : CTAB;
        const float* QI = isY ? YINV : CINV;
        float qt[8], qi[8];
        {
            float4 a = *(const float4*)&QT[j * 8];
            float4 c = *(const float4*)&QT[j * 8 + 4];
            qt[0] = a.x; qt[1] = a.y; qt[2] = a.z; qt[3] = a.w;
            qt[4] = c.x; qt[5] = c.y; qt[6] = c.z; qt[7] = c.w;
            float4 ai = *(const float4*)&QI[j * 8];
            float4 ci = *(const float4*)&QI[j * 8 + 4];
            qi[0] = ai.x; qi[1] = ai.y; qi[2] = ai.z; qi[3] = ai.w;
            qi[4] = ci.x; qi[5] = ci.y; qi[6] = ci.z; qi[7] = ci.w;
        }
        const float RC = 0.70710678118654752440f;
        float au = (j == 0) ? RC : 1.0f;
#pragma unroll
        for (int v = 0; v < 8; ++v) {
            float av    = (v == 0) ? RC : 1.0f;
            float a2    = au * av;             // ALPHA2 fp32 product
            float scale = a2 * 0.25f;          // _SCALE
            float dct   = scale * R[v];
            // xq = rn(dct/qt): Markstein (y = rn(1/qt) const)
            float yv  = qi[v];
            float q0  = dct * yv;
            float rr  = fmaf(-qt[v], q0, dct);
            float xq  = fmaf(rr, yv, q0);
            float rd    = rintf(xq);           // half-to-even
            float d     = xq - rd;
            float cube  = (d * d) * d;
            float qq    = rd + cube;
            float deq   = qq * qt[v];
            G[v] = deq * a2;
        }
    };

    // --- LOCKSTEP pair of Y blocks: shared fences, 2x work per LDS wait
    auto dctPairY = [&](int Rb0, int Rb1) {
#pragma clang fp contract(off)
        float X0[8], X1[8];
#pragma unroll
        for (int x = 0; x < 8; ++x) X0[x] = W[Rb0 + x * YS3 + j];
#pragma unroll
        for (int x = 0; x < 8; ++x) X1[x] = W[Rb1 + x * YS3 + j];
        WFENCE();
        float T0[8], T1[8];
        pass8(X0, T0); pass8(X1, T1);
        scat(Rb0, YS3, T0); scat(Rb1, YS3, T1);
        WFENCE();
        gath(Rb0, YS3, X0); gath(Rb1, YS3, X1);    // reuse X as Tt
        WFENCE();
        pass8(X0, T0); pass8(X1, T1);              // raw dct rows
        float G0[8], G1[8];
        quant(T0, G0, true); quant(T1, G1, true);
        scat(Rb0, YS3, G0); scat(Rb1, YS3, G1);
        WFENCE();
        gath(Rb0, YS3, X0); gath(Rb1, YS3, X1);    // Gt
        WFENCE();
        pass8(X0, T0); pass8(X1, T1);              // T2
        scat(Rb0, YS3, T0); scat(Rb1, YS3, T1);
        WFENCE();
        gath(Rb0, YS3, X0); gath(Rb1, YS3, X1);    // T2t
        WFENCE();
        pass8(X0, T0); pass8(X1, T1);
#pragma unroll
        for (int k = 0; k < 8; ++k) { T0[k] = 0.25f * T0[k] + 128.f;
                                      T1[k] = 0.25f * T1[k] + 128.f; }
        *(f4*)&W[Rb0 + j * YS3]     = (f4){T0[0], T0[1], T0[2], T0[3]};
        *(f4*)&W[Rb0 + j * YS3 + 4] = (f4){T0[4], T0[5], T0[6], T0[7]};
        *(f4*)&W[Rb1 + j * YS3]     = (f4){T1[0], T1[1], T1[2], T1[3]};
        *(f4*)&W[Rb1 + j * YS3 + 4] = (f4){T1[4], T1[5], T1[6], T1[7]};
    };

    // --- single chroma block (unchanged structure)
    auto dctChroma = [&](int Rb) {
#pragma clang fp contract(off)
        float X[8], T[8], G[8];
#pragma unroll
        for (int x = 0; x < 8; ++x) X[x] = W[Rb + x * CS3 + j] - 128.f;
        WFENCE();
        pass8(X, T);
        scat(Rb, CS3, T);
        WFENCE();
        gath(Rb, CS3, X);
        WFENCE();
        pass8(X, T);
        quant(T, G, false);
        scat(Rb, CS3, G);
        WFENCE();
        gath(Rb, CS3, X);
        WFENCE();
        pass8(X, T);
        scat(Rb, CS3, T);
        WFENCE();
        gath(Rb, CS3, X);
        WFENCE();
        pass8(X, T);
#pragma unroll
        for (int k = 0; k < 8; ++k) T[k] = 0.25f * T[k] + 128.f;
        *(f4*)&W[Rb + j * CS3]     = (f4){T[0], T[1], T[2], T[3]};
        *(f4*)&W[Rb + j * CS3 + 4] = (f4){T[4], T[5], T[6], T[7]};
    };

    auto outputT = [&](size_t gb, int P) {
#pragma clang fp contract(off)
        const float INV255 = 1.0f / 255.0f;
        f4 ya = *(const f4*)&W[OY + pr * YS3 + 32 * P + c4];
        f4 yb = *(const f4*)&W[OY + (pr + 1) * YS3 + 32 * P + c4];
        f2 cbp = *(const f2*)&W[OCB + rp * CS3 + 16 * P + c8 * 2];
        f2 crp = *(const f2*)&W[OCR + rp * CS3 + 16 * P + c8 * 2];
        float cb0 = cbp[0] - 128.f, cb1 = cbp[1] - 128.f;   // +SHIFT2 sep add
        float cr0 = crp[0] - 128.f, cr1 = crp[1] - 128.f;
        f4 cbm = {cb0, cb0, cb1, cb1};
        f4 crm = {cr0, cr0, cr1, cr1};
        f4 z = 0.f, m255 = 255.f;
#pragma unroll
        for (int row = 0; row < 2; ++row) {
            f4 yy = row ? yb : ya;
            f4 rv = yy + (crm * 1.402f);
            f4 gv = (yy + (cbm * -0.344136f)) + (crm * -0.714136f);
            f4 bv = yy + (cbm * 1.772f);
            rv = __builtin_elementwise_max(__builtin_elementwise_min(rv, m255), z) * INV255;
            gv = __builtin_elementwise_max(__builtin_elementwise_min(gv, m255), z) * INV255;
            bv = __builtin_elementwise_max(__builtin_elementwise_min(bv, m255), z) * INV255;
            size_t base = gb + (size_t)row * WW;
            *(f4*)(out + base)             = rv;
            *(f4*)(out + base + plane)     = gv;
            *(f4*)(out + base + 2 * plane) = bv;
        }
    };

    // ---- schedule --------------------------------------------------------
    f4 L1[6], L2[6];
    loadT(L1, gbase0);
    loadT(L2, gbase1);                 // all 12 loads in flight

    // basis (np-exact: int mult, fp64 pi-mult/div, fp64 cos, fp32 cast);
    // each lane computes its own element, broadcast via v_readlane (no LDS)
    {
        int x = lane >> 3, u = lane & 7;
        double arg = (double)((2 * x + 1) * u) * 3.14159265358979323846 / 16.0;
        int bvi = __float_as_int((float)cos(arg));
#pragma unroll
        for (int k = 0; k < 32; ++k) {
            As2[k][0] = __int_as_float(__builtin_amdgcn_readlane(bvi, 2 * k));
            As2[k][1] = __int_as_float(__builtin_amdgcn_readlane(bvi, 2 * k + 1));
        }
    }

    stageT(L1, 0);
    stageT(L2, 1);
    WFENCE();                          // stage visible before DCT reads

    // dense DCT: Y pair lockstep (rows 0-7 and 8-15), then chroma
    dctPairY(OY + 8 * g, OY + 544 + 8 * g);
    WFENCE();
    {
        int Rb = (g < 4) ? (OCB + 8 * g) : (OCR + 8 * (g - 4));
        dctChroma(Rb);
    }
    WFENCE();                          // all results visible before output

    outputT(gbase0, 0);
    outputT(gbase1, 1);
}

extern "C" void kernel_launch(void* const* d_in, const int* in_sizes, int n_in,
                              void* d_out, int out_size, void* d_ws, size_t ws_size,
                              hipStream_t stream)
{
    const float* x = (const float*)d_in[0];
    float* o = (float*)d_out;
    int batch  = in_sizes[0] / (3 * HH * WW);   // 32
    int blocks = batch * 256 / 4;               // 2048
    jpeg_fused<<<blocks, 256, 0, stream>>>(x, o);
}